// Round 18
// baseline (264.473 us; speedup 1.0000x reference)
//
#include <hip/hip_runtime.h>
#include <hip/hip_bf16.h>
#include <math.h>

#define DIM 192
#define NB  16
#define NH  64
#define NW  64
#define NT  4096   // NH*NW

#define BN   48    // qkv block N-tile (cols of W per block)
#define NKG  24    // 192/8 k-granules

typedef __attribute__((ext_vector_type(8))) short short8;
typedef __attribute__((ext_vector_type(4))) float f32x4;
typedef __attribute__((ext_vector_type(2))) unsigned int u32x2;
typedef __attribute__((address_space(3))) void* as3_void;
typedef const __attribute__((address_space(1))) void* as1_cvoid;

__device__ __forceinline__ unsigned short f2bf(float x) {
    unsigned int u = __float_as_uint(x);
    u = u + 0x7fffu + ((u >> 16) & 1u);
    return (unsigned short)(u >> 16);
}
__device__ __forceinline__ float bf2f(unsigned short h) {
    return __uint_as_float(((unsigned int)h) << 16);
}
__device__ __forceinline__ void gload16(const void* g, void* l) {
    __builtin_amdgcn_global_load_lds((as1_cvoid)g, (as3_void)l, 16, 0, 0);
}

// ---------------------------------------------------------------------------
// Kernel 1: prep.
__global__ void k_prep(const float* __restrict__ w1, const float* __restrict__ w3,
                       const float* __restrict__ w5, const float* __restrict__ alpha,
                       const float* __restrict__ Wk, const float* __restrict__ Wv,
                       const float* __restrict__ Wr, const float* __restrict__ Wo,
                       float* __restrict__ wc,
                       unsigned short* __restrict__ Whi,
                       unsigned short* __restrict__ Wlo) {
    int bid = blockIdx.x, tid = threadIdx.x;
    if (bid == 0) {
        if (tid < DIM) {
            int c = tid;
            float a0 = alpha[0], a1 = alpha[1], a2 = alpha[2], a3 = alpha[3];
            #pragma unroll
            for (int kh = 0; kh < 5; ++kh)
                #pragma unroll
                for (int kw = 0; kw < 5; ++kw) {
                    float v = a3 * w5[c * 25 + kh * 5 + kw];
                    if (kh >= 1 && kh <= 3 && kw >= 1 && kw <= 3)
                        v += a2 * w3[c * 9 + (kh - 1) * 3 + (kw - 1)];
                    if (kh == 2 && kw == 2)
                        v += a0 + a1 * w1[c];
                    wc[c * 25 + kh * 5 + kw] = v;
                }
        }
        return;
    }
    int e = (bid - 1) * 256 + tid;
    if (e >= 4 * DIM * DIM) return;
    int mat = e / (DIM * DIM);
    int idx = e - mat * DIM * DIM;
    const float* W = (mat == 0) ? Wk : (mat == 1 ? Wv : (mat == 2 ? Wr : Wo));
    float v = W[idx];
    unsigned short h = f2bf(v);
    Whi[e] = h;
    Wlo[e] = f2bf(v - bf2f(h));
}

// ---------------------------------------------------------------------------
// Kernel 2: depthwise 5x5 conv (unchanged; xs IS re-read by qkv -> normal stores).
__global__ __launch_bounds__(192) void k_conv(const float* __restrict__ x,
                                              const float* __restrict__ wc,
                                              unsigned short* __restrict__ xs_hi,
                                              unsigned short* __restrict__ xs_lo) {
    int c  = threadIdx.x;
    int bh = blockIdx.x;
    int b = bh >> 6, h = bh & 63;
    const float* xb = x + (size_t)b * NT * DIM + c;
    size_t obase = ((size_t)b * NT + (size_t)h * NW) * DIM + c;

    float wgt[25];
    #pragma unroll
    for (int j = 0; j < 25; ++j) wgt[j] = wc[c * 25 + j];

    const float* rowp[5];
    bool rok[5];
    #pragma unroll
    for (int dh = 0; dh < 5; ++dh) {
        int hh = h + dh - 2;
        rok[dh] = (hh >= 0 && hh < NH);
        rowp[dh] = xb + (size_t)(rok[dh] ? hh : 0) * NW * DIM;
    }

    float win[5][5];
    #pragma unroll
    for (int dh = 0; dh < 5; ++dh) {
        win[dh][0] = 0.f; win[dh][1] = 0.f; win[dh][2] = 0.f;
        win[dh][3] = rok[dh] ? rowp[dh][(size_t)0 * DIM] : 0.f;
        win[dh][4] = rok[dh] ? rowp[dh][(size_t)1 * DIM] : 0.f;
    }

    for (int w = 0; w < NW; ++w) {
        int wcol = w + 2;
        bool cok = (wcol < NW);
        #pragma unroll
        for (int dh = 0; dh < 5; ++dh) {
            win[dh][0] = win[dh][1];
            win[dh][1] = win[dh][2];
            win[dh][2] = win[dh][3];
            win[dh][3] = win[dh][4];
            win[dh][4] = (rok[dh] && cok) ? rowp[dh][(size_t)wcol * DIM] : 0.f;
        }
        float acc = 0.f;
        #pragma unroll
        for (int dh = 0; dh < 5; ++dh)
            #pragma unroll
            for (int dw = 0; dw < 5; ++dw)
                acc = fmaf(win[dh][dw], wgt[dh * 5 + dw], acc);
        unsigned short hb = f2bf(acc);
        xs_hi[obase + (size_t)w * DIM] = hb;
        xs_lo[obase + (size_t)w * DIM] = f2bf(acc - bf2f(hb));
    }
}

// ---------------------------------------------------------------------------
// Kernel 3: k/v/r projections — proven config; CHANGE: output stores are
// NON-TEMPORAL (147 MB of read-never-in-this-kernel data no longer cycles
// through the per-XCD L2, keeping xs A-tiles resident).

#define LOADA(AH, AL, KC)                                                    \
    {                                                                        \
        _Pragma("unroll")                                                    \
        for (int mf = 0; mf < 4; ++mf) {                                     \
            size_t a = (size_t)(arow + mf * 16) * DIM + (KC) * 32 + kofs;    \
            AH[mf] = *(const short8*)&xs_hi[a];                              \
            AL[mf] = *(const short8*)&xs_lo[a];                              \
        }                                                                    \
    }

#define LOADB(BH, BL, KC)                                                    \
    {                                                                        \
        _Pragma("unroll")                                                    \
        for (int nf = 0; nf < 3; ++nf) {                                     \
            BH[nf] = *(const short8*)&Bs[0][(KC) * 4 + lkg][nf * 16 + l15][0]; \
            BL[nf] = *(const short8*)&Bs[1][(KC) * 4 + lkg][nf * 16 + l15][0]; \
        }                                                                    \
    }

#define COMP(AH, AL, BH, BL)                                                 \
    {                                                                        \
        _Pragma("unroll")                                                    \
        for (int mf = 0; mf < 4; ++mf)                                       \
            _Pragma("unroll")                                                \
            for (int nf = 0; nf < 3; ++nf)                                   \
                acc[mf][nf] = __builtin_amdgcn_mfma_f32_16x16x32_bf16(       \
                    AH[mf], BH[nf], acc[mf][nf], 0, 0, 0);                   \
        _Pragma("unroll")                                                    \
        for (int mf = 0; mf < 4; ++mf)                                       \
            _Pragma("unroll")                                                \
            for (int nf = 0; nf < 3; ++nf)                                   \
                acc[mf][nf] = __builtin_amdgcn_mfma_f32_16x16x32_bf16(       \
                    AH[mf], BL[nf], acc[mf][nf], 0, 0, 0);                   \
        _Pragma("unroll")                                                    \
        for (int mf = 0; mf < 4; ++mf)                                       \
            _Pragma("unroll")                                                \
            for (int nf = 0; nf < 3; ++nf)                                   \
                acc[mf][nf] = __builtin_amdgcn_mfma_f32_16x16x32_bf16(       \
                    AL[mf], BH[nf], acc[mf][nf], 0, 0, 0);                   \
    }

#define FENCE __builtin_amdgcn_sched_barrier(0)

__global__ __launch_bounds__(256, 2) void k_gemm_qkv_ws(
        const unsigned short* __restrict__ xs_hi,
        const unsigned short* __restrict__ xs_lo,
        const unsigned short* __restrict__ Whi,
        const unsigned short* __restrict__ Wlo,
        float* __restrict__ kT, float* __restrict__ vT, float* __restrict__ srT) {
    __shared__ __align__(16) char smem[49920];
    short (*Bs)[NKG][BN][8] = (short (*)[NKG][BN][8])smem;
    float* Es = (float*)smem;

    const int tid  = threadIdx.x;
    const int lane = tid & 63;
    const int wid  = tid >> 6;
    const int l15  = lane & 15;
    const int lkg  = lane >> 4;
    const int kofs = lkg * 8;

    const int bid   = blockIdx.x;
    const int xcd   = bid & 7;
    const int ix    = bid >> 3;
    const int mtile = xcd * 32 + ix / 12;
    const int sm    = ix % 12;
    const int slice = sm & 3;
    const int mat   = sm >> 2;
    const int n0    = slice * BN;

    const unsigned short* Wh = Whi + mat * (DIM * DIM);
    const unsigned short* Wl = Wlo + mat * (DIM * DIM);
    float* Out = (mat == 0) ? kT : (mat == 1 ? vT : srT);

    #pragma unroll
    for (int r = 0; r < 9; ++r) {
        int g  = r * 256 + tid;
        int g2 = (g >= 1152) ? g - 1152 : g;
        const unsigned short* src = (g >= 1152) ? Wl : Wh;
        int kg  = g2 / BN;
        int col = g2 - kg * BN;
        int doff = (r * 256 + wid * 64) * 16;
        gload16(src + (size_t)(n0 + col) * DIM + kg * 8, (char*)smem + doff);
    }

    const int mbase = mtile * 256 + wid * 64;
    const int arow  = mbase + l15;

    f32x4 acc[4][3];
    #pragma unroll
    for (int i = 0; i < 4; ++i)
        #pragma unroll
        for (int j = 0; j < 3; ++j)
            acc[i][j] = (f32x4){0.f, 0.f, 0.f, 0.f};

    short8 ah0[4], al0[4], ah1[4], al1[4], ah2[4], al2[4];
    short8 bh0[3], bl0[3], bh1[3], bl1[3];

    LOADA(ah0, al0, 0)
    LOADA(ah1, al1, 1)
    LOADA(ah2, al2, 2)
    __syncthreads();

    LOADB(bh0, bl0, 0)
    LOADB(bh1, bl1, 1)
    FENCE;
    COMP(ah0, al0, bh0, bl0)
    FENCE;
    LOADA(ah0, al0, 3)
    LOADB(bh0, bl0, 2)
    FENCE;
    COMP(ah1, al1, bh1, bl1)
    FENCE;
    LOADA(ah1, al1, 4)
    LOADB(bh1, bl1, 3)
    FENCE;
    COMP(ah2, al2, bh0, bl0)
    FENCE;
    LOADA(ah2, al2, 5)
    LOADB(bh0, bl0, 4)
    FENCE;
    COMP(ah0, al0, bh1, bl1)
    FENCE;
    LOADB(bh1, bl1, 5)
    FENCE;
    COMP(ah1, al1, bh0, bl0)
    FENCE;
    COMP(ah2, al2, bh1, bl1)

    __syncthreads();
    {
        const int tloc = wid * 64 + lkg * 4;
        #pragma unroll
        for (int mf = 0; mf < 4; ++mf)
            #pragma unroll
            for (int nf = 0; nf < 3; ++nf) {
                int row = nf * 16 + l15;
                *(f32x4*)&Es[row * 260 + tloc + mf * 16] = acc[mf][nf];
            }
    }
    __syncthreads();
    {
        const int tblk = (mtile * 256) & 4095;
        const int b    = (mtile * 256) >> 12;
        #pragma unroll
        for (int r = 0; r < 12; ++r) {
            int gg  = r * 256 + tid;
            int row = gg >> 6;
            int c4  = (gg & 63) * 4;
            f32x4 v = *(const f32x4*)&Es[row * 260 + c4];
            if (mat == 2) {
                v.x = 1.0f / (1.0f + expf(-v.x));
                v.y = 1.0f / (1.0f + expf(-v.y));
                v.z = 1.0f / (1.0f + expf(-v.z));
                v.w = 1.0f / (1.0f + expf(-v.w));
            }
            __builtin_nontemporal_store(v,
                (f32x4*)&Out[((size_t)(b * DIM + n0 + row)) * NT + tblk + c4]);
        }
    }
}

// ---------------------------------------------------------------------------
// Kernel 4: bidirectional WKV4 + fused sr*y + bf16 hi/lo split.
// CHANGE: read-once inputs via nontemporal loads; z-plane stores nontemporal.
__global__ __launch_bounds__(256) void k_wkv(
        const float* __restrict__ kT, const float* __restrict__ vT,
        const float* __restrict__ srT, const float* __restrict__ decay,
        const float* __restrict__ boost,
        unsigned short* __restrict__ z_hi, unsigned short* __restrict__ z_lo) {
    __shared__ float sa[256], sb[256];
    int bc = blockIdx.x;
    int c = bc % DIM;
    size_t base = (size_t)bc * NT;
    int tid = threadIdx.x;
    int t0 = tid * 16;

    float w  = decay[c] * (1.0f / 4096.0f);
    float u  = boost[c] * (1.0f / 4096.0f);
    float ew = expf(-w);
    float eu = expf(u);

    float ek[16], ekv[16], vv[16];
    #pragma unroll
    for (int j = 0; j < 16; j += 4) {
        f32x4 k4 = __builtin_nontemporal_load((const f32x4*)&kT[base + t0 + j]);
        f32x4 v4 = __builtin_nontemporal_load((const f32x4*)&vT[base + t0 + j]);
        ek[j + 0] = expf(k4.x); ek[j + 1] = expf(k4.y);
        ek[j + 2] = expf(k4.z); ek[j + 3] = expf(k4.w);
        vv[j + 0] = v4.x; vv[j + 1] = v4.y; vv[j + 2] = v4.z; vv[j + 3] = v4.w;
        ekv[j + 0] = ek[j + 0] * v4.x; ekv[j + 1] = ek[j + 1] * v4.y;
        ekv[j + 2] = ek[j + 2] * v4.z; ekv[j + 3] = ek[j + 3] * v4.w;
    }

    float r = ew * ew; r = r * r; r = r * r; r = r * r;   // ew^16

    float La = 0.f, Lb = 0.f;
    #pragma unroll
    for (int j = 0; j < 16; ++j) { La = fmaf(ew, La, ekv[j]); Lb = fmaf(ew, Lb, ek[j]); }
    sa[tid] = La; sb[tid] = Lb;
    __syncthreads();
    float f = r;
    for (int d = 1; d < 256; d <<= 1) {
        float ta = (tid >= d) ? sa[tid - d] : 0.f;
        float tb_ = (tid >= d) ? sb[tid - d] : 0.f;
        __syncthreads();
        sa[tid] = fmaf(f, ta, sa[tid]);
        sb[tid] = fmaf(f, tb_, sb[tid]);
        __syncthreads();
        f = f * f;
    }
    float Ca = (tid > 0) ? sa[tid - 1] : 0.f;
    float Cb = (tid > 0) ? sb[tid - 1] : 0.f;
    __syncthreads();

    float Ra = 0.f, Rb = 0.f;
    #pragma unroll
    for (int j = 15; j >= 0; --j) { Ra = fmaf(ew, Ra, ekv[j]); Rb = fmaf(ew, Rb, ek[j]); }
    sa[255 - tid] = Ra; sb[255 - tid] = Rb;
    __syncthreads();
    f = r;
    for (int d = 1; d < 256; d <<= 1) {
        float ta = (tid >= d) ? sa[tid - d] : 0.f;
        float tb_ = (tid >= d) ? sb[tid - d] : 0.f;
        __syncthreads();
        sa[tid] = fmaf(f, ta, sa[tid]);
        sb[tid] = fmaf(f, tb_, sb[tid]);
        __syncthreads();
        f = f * f;
    }
    float Da = (tid < 255) ? sa[254 - tid] : 0.f;
    float Db = (tid < 255) ? sb[254 - tid] : 0.f;

    float ab[16], bb[16];
    {
        float a = Da, bv = Db;
        #pragma unroll
        for (int j = 15; j >= 0; --j) {
            ab[j] = a; bb[j] = bv;
            a  = fmaf(ew, a, ekv[j]);
            bv = fmaf(ew, bv, ek[j]);
        }
    }
    float outv[16];
    {
        float a = Ca, bv = Cb;
        #pragma unroll
        for (int j = 0; j < 16; ++j) {
            float af = a, bf = bv;
            a  = fmaf(ew, a, ekv[j]);
            bv = fmaf(ew, bv, ek[j]);
            float euk = eu * ek[j];
            float num = af + ab[j] + euk * vv[j];
            float den = bf + bb[j] + euk;
            outv[j] = num / den;
        }
    }
    unsigned short zh[16], zl[16];
    #pragma unroll
    for (int j = 0; j < 16; j += 4) {
        f32x4 s4 = __builtin_nontemporal_load((const f32x4*)&srT[base + t0 + j]);
        float zz0 = s4.x * outv[j + 0];
        float zz1 = s4.y * outv[j + 1];
        float zz2 = s4.z * outv[j + 2];
        float zz3 = s4.w * outv[j + 3];
        zh[j + 0] = f2bf(zz0); zl[j + 0] = f2bf(zz0 - bf2f(zh[j + 0]));
        zh[j + 1] = f2bf(zz1); zl[j + 1] = f2bf(zz1 - bf2f(zh[j + 1]));
        zh[j + 2] = f2bf(zz2); zl[j + 2] = f2bf(zz2 - bf2f(zh[j + 2]));
        zh[j + 3] = f2bf(zz3); zl[j + 3] = f2bf(zz3 - bf2f(zh[j + 3]));
    }
    __builtin_nontemporal_store(*(const short8*)&zh[0], (short8*)&z_hi[base + t0]);
    __builtin_nontemporal_store(*(const short8*)&zh[8], (short8*)&z_hi[base + t0 + 8]);
    __builtin_nontemporal_store(*(const short8*)&zl[0], (short8*)&z_lo[base + t0]);
    __builtin_nontemporal_store(*(const short8*)&zl[8], (short8*)&z_lo[base + t0 + 8]);
}

// ---------------------------------------------------------------------------
// Kernel 5: output projection. CHANGE: z-plane loads nontemporal (read-once),
// final out stores nontemporal (never re-read).

#define OSTAGE(BF, KC)                                                       \
    {                                                                        \
        _Pragma("unroll")                                                    \
        for (int pass = 0; pass < 2; ++pass) {                               \
            int t = stq * 4 + pass * 64;                                     \
            size_t rb = ((size_t)(b * DIM + (KC) * 32 + cp * 2)) * NT + t0 + t; \
            u32x2 h0 = __builtin_nontemporal_load((const u32x2*)&z_hi[rb]);  \
            u32x2 h1 = __builtin_nontemporal_load((const u32x2*)&z_hi[rb + NT]); \
            u32x2 l0 = __builtin_nontemporal_load((const u32x2*)&z_lo[rb]);  \
            u32x2 l1 = __builtin_nontemporal_load((const u32x2*)&z_lo[rb + NT]); \
            _Pragma("unroll")                                                \
            for (int j = 0; j < 4; ++j) {                                    \
                unsigned int a0 = (j < 2) ? h0.x : h0.y;                     \
                unsigned int a1 = (j < 2) ? h1.x : h1.y;                     \
                unsigned int c0 = (j < 2) ? l0.x : l0.y;                     \
                unsigned int c1 = (j < 2) ? l1.x : l1.y;                     \
                int sh = 16 * (j & 1);                                       \
                unsigned int hw = ((a0 >> sh) & 0xffffu)                     \
                                | (((a1 >> sh) & 0xffffu) << 16);            \
                unsigned int lw = ((c0 >> sh) & 0xffffu)                     \
                                | (((c1 >> sh) & 0xffffu) << 16);            \
                *(unsigned int*)&Ah[BF][t + j][cp * 2] = hw;                 \
                *(unsigned int*)&Al[BF][t + j][cp * 2] = lw;                 \
            }                                                                \
        }                                                                    \
    }

#define OCOMP(BF, KC)                                                        \
    {                                                                        \
        short8 afh[4], afl[4], bfh[3], bfl[3];                               \
        _Pragma("unroll")                                                    \
        for (int mf = 0; mf < 4; ++mf) {                                     \
            int row = wm * 64 + mf * 16 + l15;                               \
            afh[mf] = *(const short8*)&Ah[BF][row][lkg * 8];                 \
            afl[mf] = *(const short8*)&Al[BF][row][lkg * 8];                 \
        }                                                                    \
        _Pragma("unroll")                                                    \
        for (int nf = 0; nf < 3; ++nf) {                                     \
            size_t wb = (size_t)(n0 + wn * 48 + nf * 16 + l15) * DIM + (KC) * 32 + lkg * 8; \
            bfh[nf] = *(const short8*)&Wohi[wb];                             \
            bfl[nf] = *(const short8*)&Wolo[wb];                             \
        }                                                                    \
        _Pragma("unroll")                                                    \
        for (int mf = 0; mf < 4; ++mf)                                       \
            _Pragma("unroll")                                                \
            for (int nf = 0; nf < 3; ++nf)                                   \
                acc[mf][nf] = __builtin_amdgcn_mfma_f32_16x16x32_bf16(       \
                    afh[mf], bfh[nf], acc[mf][nf], 0, 0, 0);                 \
        _Pragma("unroll")                                                    \
        for (int mf = 0; mf < 4; ++mf)                                       \
            _Pragma("unroll")                                                \
            for (int nf = 0; nf < 3; ++nf)                                   \
                acc[mf][nf] = __builtin_amdgcn_mfma_f32_16x16x32_bf16(       \
                    afh[mf], bfl[nf], acc[mf][nf], 0, 0, 0);                 \
        _Pragma("unroll")                                                    \
        for (int mf = 0; mf < 4; ++mf)                                       \
            _Pragma("unroll")                                                \
            for (int nf = 0; nf < 3; ++nf)                                   \
                acc[mf][nf] = __builtin_amdgcn_mfma_f32_16x16x32_bf16(       \
                    afl[mf], bfh[nf], acc[mf][nf], 0, 0, 0);                 \
    }

__global__ __launch_bounds__(256) void k_gemm_out_mfma(
        const unsigned short* __restrict__ z_hi,
        const unsigned short* __restrict__ z_lo,
        const unsigned short* __restrict__ Wohi,
        const unsigned short* __restrict__ Wolo,
        float* __restrict__ out) {
    __shared__ __align__(16) unsigned short Ah[2][128][40];
    __shared__ __align__(16) unsigned short Al[2][128][40];

    const int tid  = threadIdx.x;
    const int lane = tid & 63;
    const int wid  = tid >> 6;
    const int wm = wid >> 1, wn = wid & 1;
    const int l15 = lane & 15;
    const int lkg = lane >> 4;

    const int bid = blockIdx.x;
    const int xcd = bid & 7;
    const int ixx = bid >> 3;
    const int mt  = xcd * 64 + (ixx >> 1);
    const int n0  = (ixx & 1) * 96;
    const int m0  = mt * 128;
    const int b   = m0 >> 12;
    const int t0  = m0 & 4095;

    const int cp  = tid >> 4;
    const int stq = tid & 15;

    f32x4 acc[4][3];
    #pragma unroll
    for (int i = 0; i < 4; ++i)
        #pragma unroll
        for (int j = 0; j < 3; ++j)
            acc[i][j] = (f32x4){0.f, 0.f, 0.f, 0.f};

    OSTAGE(0, 0)
    __syncthreads();
    #pragma unroll
    for (int kc = 0; kc < 6; ++kc) {
        if (kc < 5) OSTAGE((kc + 1) & 1, kc + 1)
        OCOMP(kc & 1, kc)
        __syncthreads();
    }

    #pragma unroll
    for (int mf = 0; mf < 4; ++mf) {
        int trow = m0 + wm * 64 + mf * 16 + lkg * 4;
        #pragma unroll
        for (int nf = 0; nf < 3; ++nf) {
            int ncol = n0 + wn * 48 + nf * 16 + l15;
            #pragma unroll
            for (int j = 0; j < 4; ++j)
                __builtin_nontemporal_store(acc[mf][nf][j],
                    &out[(size_t)(trow + j) * DIM + ncol]);
        }
    }
}

// ---------------------------------------------------------------------------
extern "C" void kernel_launch(void* const* d_in, const int* in_sizes, int n_in,
                              void* d_out, int out_size, void* d_ws, size_t ws_size,
                              hipStream_t stream) {
    const float* x     = (const float*)d_in[0];
    const float* w1    = (const float*)d_in[1];
    const float* w3    = (const float*)d_in[2];
    const float* w5    = (const float*)d_in[3];
    const float* alpha = (const float*)d_in[4];
    const float* Wk    = (const float*)d_in[5];
    const float* Wv    = (const float*)d_in[6];
    const float* Wr    = (const float*)d_in[7];
    const float* Wo    = (const float*)d_in[8];
    const float* decay = (const float*)d_in[9];
    const float* boost = (const float*)d_in[10];
    float* out = (float*)d_out;
    float* ws  = (float*)d_ws;

    const size_t BIG = (size_t)NB * NT * DIM;

    float* wc = ws;
    unsigned short* Whi = (unsigned short*)(ws + 8192);
    unsigned short* Wlo = (unsigned short*)(ws + 81920);
    unsigned short* xs_hi = (unsigned short*)(ws + 155648);
    unsigned short* xs_lo = xs_hi + BIG;
    float* kT  = ws + 12738560;
    float* vT  = kT + BIG;
    float* srT = vT + BIG;
    unsigned short* z_hi = (unsigned short*)(ws + 155648);  // overlays xs
    unsigned short* z_lo = z_hi + BIG;

    hipLaunchKernelGGL(k_prep, dim3(577), dim3(256), 0, stream,
                       w1, w3, w5, alpha, Wk, Wv, Wr, Wo, wc, Whi, Wlo);
    hipLaunchKernelGGL(k_conv, dim3(NB * NH), dim3(DIM), 0, stream,
                       x, wc, xs_hi, xs_lo);
    hipLaunchKernelGGL(k_gemm_qkv_ws, dim3(3072), dim3(256), 0, stream,
                       xs_hi, xs_lo, Whi, Wlo, kT, vT, srT);
    hipLaunchKernelGGL(k_wkv, dim3(NB * DIM), dim3(256), 0, stream,
                       kT, vT, srT, decay, boost, z_hi, z_lo);
    hipLaunchKernelGGL(k_gemm_out_mfma, dim3(1024), dim3(256), 0, stream,
                       z_hi, z_lo, Whi + 3 * DIM * DIM, Wlo + 3 * DIM * DIM, out);
}

// Round 19
// 216.290 us; speedup vs baseline: 1.2228x; 1.2228x over previous
//
#include <hip/hip_runtime.h>
#include <hip/hip_bf16.h>
#include <math.h>

#define DIM 192
#define NB  16
#define NH  64
#define NW  64
#define NT  4096   // NH*NW

#define BN   48    // qkv block N-tile (cols of W per block)
#define NKG  24    // 192/8 k-granules

typedef __attribute__((ext_vector_type(8))) short short8;
typedef __attribute__((ext_vector_type(4))) float f32x4;
typedef __attribute__((address_space(3))) void* as3_void;
typedef const __attribute__((address_space(1))) void* as1_cvoid;

__device__ __forceinline__ unsigned short f2bf(float x) {
    unsigned int u = __float_as_uint(x);
    u = u + 0x7fffu + ((u >> 16) & 1u);
    return (unsigned short)(u >> 16);
}
__device__ __forceinline__ float bf2f(unsigned short h) {
    return __uint_as_float(((unsigned int)h) << 16);
}
__device__ __forceinline__ void gload16(const void* g, void* l) {
    __builtin_amdgcn_global_load_lds((as1_cvoid)g, (as3_void)l, 16, 0, 0);
}

// ---------------------------------------------------------------------------
// Kernel 1: prep.
__global__ void k_prep(const float* __restrict__ w1, const float* __restrict__ w3,
                       const float* __restrict__ w5, const float* __restrict__ alpha,
                       const float* __restrict__ Wk, const float* __restrict__ Wv,
                       const float* __restrict__ Wr, const float* __restrict__ Wo,
                       float* __restrict__ wc,
                       unsigned short* __restrict__ Whi,
                       unsigned short* __restrict__ Wlo) {
    int bid = blockIdx.x, tid = threadIdx.x;
    if (bid == 0) {
        if (tid < DIM) {
            int c = tid;
            float a0 = alpha[0], a1 = alpha[1], a2 = alpha[2], a3 = alpha[3];
            #pragma unroll
            for (int kh = 0; kh < 5; ++kh)
                #pragma unroll
                for (int kw = 0; kw < 5; ++kw) {
                    float v = a3 * w5[c * 25 + kh * 5 + kw];
                    if (kh >= 1 && kh <= 3 && kw >= 1 && kw <= 3)
                        v += a2 * w3[c * 9 + (kh - 1) * 3 + (kw - 1)];
                    if (kh == 2 && kw == 2)
                        v += a0 + a1 * w1[c];
                    wc[c * 25 + kh * 5 + kw] = v;
                }
        }
        return;
    }
    int e = (bid - 1) * 256 + tid;
    if (e >= 4 * DIM * DIM) return;
    int mat = e / (DIM * DIM);
    int idx = e - mat * DIM * DIM;
    const float* W = (mat == 0) ? Wk : (mat == 1 ? Wv : (mat == 2 ? Wr : Wo));
    float v = W[idx];
    unsigned short h = f2bf(v);
    Whi[e] = h;
    Wlo[e] = f2bf(v - bf2f(h));
}

// ---------------------------------------------------------------------------
// Kernel 2: depthwise 5x5 conv (unchanged).
__global__ __launch_bounds__(192) void k_conv(const float* __restrict__ x,
                                              const float* __restrict__ wc,
                                              unsigned short* __restrict__ xs_hi,
                                              unsigned short* __restrict__ xs_lo) {
    int c  = threadIdx.x;
    int bh = blockIdx.x;
    int b = bh >> 6, h = bh & 63;
    const float* xb = x + (size_t)b * NT * DIM + c;
    size_t obase = ((size_t)b * NT + (size_t)h * NW) * DIM + c;

    float wgt[25];
    #pragma unroll
    for (int j = 0; j < 25; ++j) wgt[j] = wc[c * 25 + j];

    const float* rowp[5];
    bool rok[5];
    #pragma unroll
    for (int dh = 0; dh < 5; ++dh) {
        int hh = h + dh - 2;
        rok[dh] = (hh >= 0 && hh < NH);
        rowp[dh] = xb + (size_t)(rok[dh] ? hh : 0) * NW * DIM;
    }

    float win[5][5];
    #pragma unroll
    for (int dh = 0; dh < 5; ++dh) {
        win[dh][0] = 0.f; win[dh][1] = 0.f; win[dh][2] = 0.f;
        win[dh][3] = rok[dh] ? rowp[dh][(size_t)0 * DIM] : 0.f;
        win[dh][4] = rok[dh] ? rowp[dh][(size_t)1 * DIM] : 0.f;
    }

    for (int w = 0; w < NW; ++w) {
        int wcol = w + 2;
        bool cok = (wcol < NW);
        #pragma unroll
        for (int dh = 0; dh < 5; ++dh) {
            win[dh][0] = win[dh][1];
            win[dh][1] = win[dh][2];
            win[dh][2] = win[dh][3];
            win[dh][3] = win[dh][4];
            win[dh][4] = (rok[dh] && cok) ? rowp[dh][(size_t)wcol * DIM] : 0.f;
        }
        float acc = 0.f;
        #pragma unroll
        for (int dh = 0; dh < 5; ++dh)
            #pragma unroll
            for (int dw = 0; dw < 5; ++dw)
                acc = fmaf(win[dh][dw], wgt[dh * 5 + dw], acc);
        unsigned short hb = f2bf(acc);
        xs_hi[obase + (size_t)w * DIM] = hb;
        xs_lo[obase + (size_t)w * DIM] = f2bf(acc - bf2f(hb));
    }
}

// ---------------------------------------------------------------------------
// Kernel 3: k/v/r projections — round-17 config exactly (W-stationary LDS,
// depth-3 A pipeline, XCD swizzle, coalesced LDS-staged epilogue, NORMAL
// stores — outputs are re-read by wkv, NT stores broke that reuse in r18).

#define LOADA(AH, AL, KC)                                                    \
    {                                                                        \
        _Pragma("unroll")                                                    \
        for (int mf = 0; mf < 4; ++mf) {                                     \
            size_t a = (size_t)(arow + mf * 16) * DIM + (KC) * 32 + kofs;    \
            AH[mf] = *(const short8*)&xs_hi[a];                              \
            AL[mf] = *(const short8*)&xs_lo[a];                              \
        }                                                                    \
    }

#define LOADB(BH, BL, KC)                                                    \
    {                                                                        \
        _Pragma("unroll")                                                    \
        for (int nf = 0; nf < 3; ++nf) {                                     \
            BH[nf] = *(const short8*)&Bs[0][(KC) * 4 + lkg][nf * 16 + l15][0]; \
            BL[nf] = *(const short8*)&Bs[1][(KC) * 4 + lkg][nf * 16 + l15][0]; \
        }                                                                    \
    }

#define COMP(AH, AL, BH, BL)                                                 \
    {                                                                        \
        _Pragma("unroll")                                                    \
        for (int mf = 0; mf < 4; ++mf)                                       \
            _Pragma("unroll")                                                \
            for (int nf = 0; nf < 3; ++nf)                                   \
                acc[mf][nf] = __builtin_amdgcn_mfma_f32_16x16x32_bf16(       \
                    AH[mf], BH[nf], acc[mf][nf], 0, 0, 0);                   \
        _Pragma("unroll")                                                    \
        for (int mf = 0; mf < 4; ++mf)                                       \
            _Pragma("unroll")                                                \
            for (int nf = 0; nf < 3; ++nf)                                   \
                acc[mf][nf] = __builtin_amdgcn_mfma_f32_16x16x32_bf16(       \
                    AH[mf], BL[nf], acc[mf][nf], 0, 0, 0);                   \
        _Pragma("unroll")                                                    \
        for (int mf = 0; mf < 4; ++mf)                                       \
            _Pragma("unroll")                                                \
            for (int nf = 0; nf < 3; ++nf)                                   \
                acc[mf][nf] = __builtin_amdgcn_mfma_f32_16x16x32_bf16(       \
                    AL[mf], BH[nf], acc[mf][nf], 0, 0, 0);                   \
    }

#define FENCE __builtin_amdgcn_sched_barrier(0)

__global__ __launch_bounds__(256, 2) void k_gemm_qkv_ws(
        const unsigned short* __restrict__ xs_hi,
        const unsigned short* __restrict__ xs_lo,
        const unsigned short* __restrict__ Whi,
        const unsigned short* __restrict__ Wlo,
        float* __restrict__ kT, float* __restrict__ vT, float* __restrict__ srT) {
    __shared__ __align__(16) char smem[49920];
    short (*Bs)[NKG][BN][8] = (short (*)[NKG][BN][8])smem;
    float* Es = (float*)smem;

    const int tid  = threadIdx.x;
    const int lane = tid & 63;
    const int wid  = tid >> 6;
    const int l15  = lane & 15;
    const int lkg  = lane >> 4;
    const int kofs = lkg * 8;

    const int bid   = blockIdx.x;
    const int xcd   = bid & 7;
    const int ix    = bid >> 3;
    const int mtile = xcd * 32 + ix / 12;
    const int sm    = ix % 12;
    const int slice = sm & 3;
    const int mat   = sm >> 2;
    const int n0    = slice * BN;

    const unsigned short* Wh = Whi + mat * (DIM * DIM);
    const unsigned short* Wl = Wlo + mat * (DIM * DIM);
    float* Out = (mat == 0) ? kT : (mat == 1 ? vT : srT);

    #pragma unroll
    for (int r = 0; r < 9; ++r) {
        int g  = r * 256 + tid;
        int g2 = (g >= 1152) ? g - 1152 : g;
        const unsigned short* src = (g >= 1152) ? Wl : Wh;
        int kg  = g2 / BN;
        int col = g2 - kg * BN;
        int doff = (r * 256 + wid * 64) * 16;
        gload16(src + (size_t)(n0 + col) * DIM + kg * 8, (char*)smem + doff);
    }

    const int mbase = mtile * 256 + wid * 64;
    const int arow  = mbase + l15;

    f32x4 acc[4][3];
    #pragma unroll
    for (int i = 0; i < 4; ++i)
        #pragma unroll
        for (int j = 0; j < 3; ++j)
            acc[i][j] = (f32x4){0.f, 0.f, 0.f, 0.f};

    short8 ah0[4], al0[4], ah1[4], al1[4], ah2[4], al2[4];
    short8 bh0[3], bl0[3], bh1[3], bl1[3];

    LOADA(ah0, al0, 0)
    LOADA(ah1, al1, 1)
    LOADA(ah2, al2, 2)
    __syncthreads();

    LOADB(bh0, bl0, 0)
    LOADB(bh1, bl1, 1)
    FENCE;
    COMP(ah0, al0, bh0, bl0)
    FENCE;
    LOADA(ah0, al0, 3)
    LOADB(bh0, bl0, 2)
    FENCE;
    COMP(ah1, al1, bh1, bl1)
    FENCE;
    LOADA(ah1, al1, 4)
    LOADB(bh1, bl1, 3)
    FENCE;
    COMP(ah2, al2, bh0, bl0)
    FENCE;
    LOADA(ah2, al2, 5)
    LOADB(bh0, bl0, 4)
    FENCE;
    COMP(ah0, al0, bh1, bl1)
    FENCE;
    LOADB(bh1, bl1, 5)
    FENCE;
    COMP(ah1, al1, bh0, bl0)
    FENCE;
    COMP(ah2, al2, bh1, bl1)

    __syncthreads();
    {
        const int tloc = wid * 64 + lkg * 4;
        #pragma unroll
        for (int mf = 0; mf < 4; ++mf)
            #pragma unroll
            for (int nf = 0; nf < 3; ++nf) {
                int row = nf * 16 + l15;
                *(f32x4*)&Es[row * 260 + tloc + mf * 16] = acc[mf][nf];
            }
    }
    __syncthreads();
    {
        const int tblk = (mtile * 256) & 4095;
        const int b    = (mtile * 256) >> 12;
        #pragma unroll
        for (int r = 0; r < 12; ++r) {
            int gg  = r * 256 + tid;
            int row = gg >> 6;
            int c4  = (gg & 63) * 4;
            f32x4 v = *(const f32x4*)&Es[row * 260 + c4];
            if (mat == 2) {
                v.x = 1.0f / (1.0f + expf(-v.x));
                v.y = 1.0f / (1.0f + expf(-v.y));
                v.z = 1.0f / (1.0f + expf(-v.z));
                v.w = 1.0f / (1.0f + expf(-v.w));
            }
            *(f32x4*)&Out[((size_t)(b * DIM + n0 + row)) * NT + tblk + c4] = v;
        }
    }
}

// ---------------------------------------------------------------------------
// Kernel 4: bidirectional WKV4 + fused sr*y + bf16 hi/lo split (round-17
// version: normal loads/stores — z planes are re-read by gemm_out).
__global__ __launch_bounds__(256) void k_wkv(
        const float* __restrict__ kT, const float* __restrict__ vT,
        const float* __restrict__ srT, const float* __restrict__ decay,
        const float* __restrict__ boost,
        unsigned short* __restrict__ z_hi, unsigned short* __restrict__ z_lo) {
    __shared__ float sa[256], sb[256];
    int bc = blockIdx.x;
    int c = bc % DIM;
    size_t base = (size_t)bc * NT;
    int tid = threadIdx.x;
    int t0 = tid * 16;

    float w  = decay[c] * (1.0f / 4096.0f);
    float u  = boost[c] * (1.0f / 4096.0f);
    float ew = expf(-w);
    float eu = expf(u);

    float ek[16], ekv[16], vv[16];
    #pragma unroll
    for (int j = 0; j < 16; j += 4) {
        float4 k4 = *(const float4*)&kT[base + t0 + j];
        float4 v4 = *(const float4*)&vT[base + t0 + j];
        ek[j + 0] = expf(k4.x); ek[j + 1] = expf(k4.y);
        ek[j + 2] = expf(k4.z); ek[j + 3] = expf(k4.w);
        vv[j + 0] = v4.x; vv[j + 1] = v4.y; vv[j + 2] = v4.z; vv[j + 3] = v4.w;
        ekv[j + 0] = ek[j + 0] * v4.x; ekv[j + 1] = ek[j + 1] * v4.y;
        ekv[j + 2] = ek[j + 2] * v4.z; ekv[j + 3] = ek[j + 3] * v4.w;
    }

    float r = ew * ew; r = r * r; r = r * r; r = r * r;   // ew^16

    float La = 0.f, Lb = 0.f;
    #pragma unroll
    for (int j = 0; j < 16; ++j) { La = fmaf(ew, La, ekv[j]); Lb = fmaf(ew, Lb, ek[j]); }
    sa[tid] = La; sb[tid] = Lb;
    __syncthreads();
    float f = r;
    for (int d = 1; d < 256; d <<= 1) {
        float ta = (tid >= d) ? sa[tid - d] : 0.f;
        float tb_ = (tid >= d) ? sb[tid - d] : 0.f;
        __syncthreads();
        sa[tid] = fmaf(f, ta, sa[tid]);
        sb[tid] = fmaf(f, tb_, sb[tid]);
        __syncthreads();
        f = f * f;
    }
    float Ca = (tid > 0) ? sa[tid - 1] : 0.f;
    float Cb = (tid > 0) ? sb[tid - 1] : 0.f;
    __syncthreads();

    float Ra = 0.f, Rb = 0.f;
    #pragma unroll
    for (int j = 15; j >= 0; --j) { Ra = fmaf(ew, Ra, ekv[j]); Rb = fmaf(ew, Rb, ek[j]); }
    sa[255 - tid] = Ra; sb[255 - tid] = Rb;
    __syncthreads();
    f = r;
    for (int d = 1; d < 256; d <<= 1) {
        float ta = (tid >= d) ? sa[tid - d] : 0.f;
        float tb_ = (tid >= d) ? sb[tid - d] : 0.f;
        __syncthreads();
        sa[tid] = fmaf(f, ta, sa[tid]);
        sb[tid] = fmaf(f, tb_, sb[tid]);
        __syncthreads();
        f = f * f;
    }
    float Da = (tid < 255) ? sa[254 - tid] : 0.f;
    float Db = (tid < 255) ? sb[254 - tid] : 0.f;

    float ab[16], bb[16];
    {
        float a = Da, bv = Db;
        #pragma unroll
        for (int j = 15; j >= 0; --j) {
            ab[j] = a; bb[j] = bv;
            a  = fmaf(ew, a, ekv[j]);
            bv = fmaf(ew, bv, ek[j]);
        }
    }
    float outv[16];
    {
        float a = Ca, bv = Cb;
        #pragma unroll
        for (int j = 0; j < 16; ++j) {
            float af = a, bf = bv;
            a  = fmaf(ew, a, ekv[j]);
            bv = fmaf(ew, bv, ek[j]);
            float euk = eu * ek[j];
            float num = af + ab[j] + euk * vv[j];
            float den = bf + bb[j] + euk;
            outv[j] = num / den;
        }
    }
    unsigned short zh[16], zl[16];
    #pragma unroll
    for (int j = 0; j < 16; j += 4) {
        float4 s4 = *(const float4*)&srT[base + t0 + j];
        float zz0 = s4.x * outv[j + 0];
        float zz1 = s4.y * outv[j + 1];
        float zz2 = s4.z * outv[j + 2];
        float zz3 = s4.w * outv[j + 3];
        zh[j + 0] = f2bf(zz0); zl[j + 0] = f2bf(zz0 - bf2f(zh[j + 0]));
        zh[j + 1] = f2bf(zz1); zl[j + 1] = f2bf(zz1 - bf2f(zh[j + 1]));
        zh[j + 2] = f2bf(zz2); zl[j + 2] = f2bf(zz2 - bf2f(zh[j + 2]));
        zh[j + 3] = f2bf(zz3); zl[j + 3] = f2bf(zz3 - bf2f(zh[j + 3]));
    }
    *(short8*)&z_hi[base + t0]     = *(const short8*)&zh[0];
    *(short8*)&z_hi[base + t0 + 8] = *(const short8*)&zh[8];
    *(short8*)&z_lo[base + t0]     = *(const short8*)&zl[0];
    *(short8*)&z_lo[base + t0 + 8] = *(const short8*)&zl[8];
}

// ---------------------------------------------------------------------------
// Kernel 5: output projection (round-17 version); the ONLY surviving NT hint:
// final out stores — nothing on-device re-reads out, so evicting it keeps
// more of z resident in L2 for OSTAGE.

#define OSTAGE(BF, KC)                                                       \
    {                                                                        \
        _Pragma("unroll")                                                    \
        for (int pass = 0; pass < 2; ++pass) {                               \
            int t = stq * 4 + pass * 64;                                     \
            size_t rb = ((size_t)(b * DIM + (KC) * 32 + cp * 2)) * NT + t0 + t; \
            uint2 h0 = *(const uint2*)&z_hi[rb];                             \
            uint2 h1 = *(const uint2*)&z_hi[rb + NT];                        \
            uint2 l0 = *(const uint2*)&z_lo[rb];                             \
            uint2 l1 = *(const uint2*)&z_lo[rb + NT];                        \
            _Pragma("unroll")                                                \
            for (int j = 0; j < 4; ++j) {                                    \
                unsigned int a0 = (j < 2) ? h0.x : h0.y;                     \
                unsigned int a1 = (j < 2) ? h1.x : h1.y;                     \
                unsigned int c0 = (j < 2) ? l0.x : l0.y;                     \
                unsigned int c1 = (j < 2) ? l1.x : l1.y;                     \
                int sh = 16 * (j & 1);                                       \
                unsigned int hw = ((a0 >> sh) & 0xffffu)                     \
                                | (((a1 >> sh) & 0xffffu) << 16);            \
                unsigned int lw = ((c0 >> sh) & 0xffffu)                     \
                                | (((c1 >> sh) & 0xffffu) << 16);            \
                *(unsigned int*)&Ah[BF][t + j][cp * 2] = hw;                 \
                *(unsigned int*)&Al[BF][t + j][cp * 2] = lw;                 \
            }                                                                \
        }                                                                    \
    }

#define OCOMP(BF, KC)                                                        \
    {                                                                        \
        short8 afh[4], afl[4], bfh[3], bfl[3];                               \
        _Pragma("unroll")                                                    \
        for (int mf = 0; mf < 4; ++mf) {                                     \
            int row = wm * 64 + mf * 16 + l15;                               \
            afh[mf] = *(const short8*)&Ah[BF][row][lkg * 8];                 \
            afl[mf] = *(const short8*)&Al[BF][row][lkg * 8];                 \
        }                                                                    \
        _Pragma("unroll")                                                    \
        for (int nf = 0; nf < 3; ++nf) {                                     \
            size_t wb = (size_t)(n0 + wn * 48 + nf * 16 + l15) * DIM + (KC) * 32 + lkg * 8; \
            bfh[nf] = *(const short8*)&Wohi[wb];                             \
            bfl[nf] = *(const short8*)&Wolo[wb];                             \
        }                                                                    \
        _Pragma("unroll")                                                    \
        for (int mf = 0; mf < 4; ++mf)                                       \
            _Pragma("unroll")                                                \
            for (int nf = 0; nf < 3; ++nf)                                   \
                acc[mf][nf] = __builtin_amdgcn_mfma_f32_16x16x32_bf16(       \
                    afh[mf], bfh[nf], acc[mf][nf], 0, 0, 0);                 \
        _Pragma("unroll")                                                    \
        for (int mf = 0; mf < 4; ++mf)                                       \
            _Pragma("unroll")                                                \
            for (int nf = 0; nf < 3; ++nf)                                   \
                acc[mf][nf] = __builtin_amdgcn_mfma_f32_16x16x32_bf16(       \
                    afh[mf], bfl[nf], acc[mf][nf], 0, 0, 0);                 \
        _Pragma("unroll")                                                    \
        for (int mf = 0; mf < 4; ++mf)                                       \
            _Pragma("unroll")                                                \
            for (int nf = 0; nf < 3; ++nf)                                   \
                acc[mf][nf] = __builtin_amdgcn_mfma_f32_16x16x32_bf16(       \
                    afl[mf], bfh[nf], acc[mf][nf], 0, 0, 0);                 \
    }

__global__ __launch_bounds__(256) void k_gemm_out_mfma(
        const unsigned short* __restrict__ z_hi,
        const unsigned short* __restrict__ z_lo,
        const unsigned short* __restrict__ Wohi,
        const unsigned short* __restrict__ Wolo,
        float* __restrict__ out) {
    __shared__ __align__(16) unsigned short Ah[2][128][40];
    __shared__ __align__(16) unsigned short Al[2][128][40];

    const int tid  = threadIdx.x;
    const int lane = tid & 63;
    const int wid  = tid >> 6;
    const int wm = wid >> 1, wn = wid & 1;
    const int l15 = lane & 15;
    const int lkg = lane >> 4;

    // 1024 blocks = 8 xcd * 64 m-tiles * 2 n-halves; n-halves consecutive.
    const int bid = blockIdx.x;
    const int xcd = bid & 7;
    const int ixx = bid >> 3;
    const int mt  = xcd * 64 + (ixx >> 1);
    const int n0  = (ixx & 1) * 96;
    const int m0  = mt * 128;
    const int b   = m0 >> 12;
    const int t0  = m0 & 4095;

    const int cp  = tid >> 4;       // 0..15 (c-pair within 32-c chunk)
    const int stq = tid & 15;       // 0..15 (t quad)

    f32x4 acc[4][3];
    #pragma unroll
    for (int i = 0; i < 4; ++i)
        #pragma unroll
        for (int j = 0; j < 3; ++j)
            acc[i][j] = (f32x4){0.f, 0.f, 0.f, 0.f};

    OSTAGE(0, 0)
    __syncthreads();
    #pragma unroll
    for (int kc = 0; kc < 6; ++kc) {
        if (kc < 5) OSTAGE((kc + 1) & 1, kc + 1)
        OCOMP(kc & 1, kc)
        __syncthreads();
    }

    #pragma unroll
    for (int mf = 0; mf < 4; ++mf) {
        int trow = m0 + wm * 64 + mf * 16 + lkg * 4;
        #pragma unroll
        for (int nf = 0; nf < 3; ++nf) {
            int ncol = n0 + wn * 48 + nf * 16 + l15;
            #pragma unroll
            for (int j = 0; j < 4; ++j)
                __builtin_nontemporal_store(acc[mf][nf][j],
                    &out[(size_t)(trow + j) * DIM + ncol]);
        }
    }
}

// ---------------------------------------------------------------------------
extern "C" void kernel_launch(void* const* d_in, const int* in_sizes, int n_in,
                              void* d_out, int out_size, void* d_ws, size_t ws_size,
                              hipStream_t stream) {
    const float* x     = (const float*)d_in[0];
    const float* w1    = (const float*)d_in[1];
    const float* w3    = (const float*)d_in[2];
    const float* w5    = (const float*)d_in[3];
    const float* alpha = (const float*)d_in[4];
    const float* Wk    = (const float*)d_in[5];
    const float* Wv    = (const float*)d_in[6];
    const float* Wr    = (const float*)d_in[7];
    const float* Wo    = (const float*)d_in[8];
    const float* decay = (const float*)d_in[9];
    const float* boost = (const float*)d_in[10];
    float* out = (float*)d_out;
    float* ws  = (float*)d_ws;

    const size_t BIG = (size_t)NB * NT * DIM;

    float* wc = ws;
    unsigned short* Whi = (unsigned short*)(ws + 8192);
    unsigned short* Wlo = (unsigned short*)(ws + 81920);
    unsigned short* xs_hi = (unsigned short*)(ws + 155648);
    unsigned short* xs_lo = xs_hi + BIG;
    float* kT  = ws + 12738560;
    float* vT  = kT + BIG;
    float* srT = vT + BIG;
    unsigned short* z_hi = (unsigned short*)(ws + 155648);  // overlays xs
    unsigned short* z_lo = z_hi + BIG;

    hipLaunchKernelGGL(k_prep, dim3(577), dim3(256), 0, stream,
                       w1, w3, w5, alpha, Wk, Wv, Wr, Wo, wc, Whi, Wlo);
    hipLaunchKernelGGL(k_conv, dim3(NB * NH), dim3(DIM), 0, stream,
                       x, wc, xs_hi, xs_lo);
    hipLaunchKernelGGL(k_gemm_qkv_ws, dim3(3072), dim3(256), 0, stream,
                       xs_hi, xs_lo, Whi, Wlo, kT, vT, srT);
    hipLaunchKernelGGL(k_wkv, dim3(NB * DIM), dim3(256), 0, stream,
                       kT, vT, srT, decay, boost, z_hi, z_lo);
    hipLaunchKernelGGL(k_gemm_out_mfma, dim3(1024), dim3(256), 0, stream,
                       z_hi, z_lo, Whi + 3 * DIM * DIM, Wlo + 3 * DIM * DIM, out);
}